// Round 1
// baseline (1013.685 us; speedup 1.0000x reference)
//
#include <hip/hip_runtime.h>
#include <math.h>

#define N_NODES 100000
#define N_EDGES 1600000
#define HID 48
#define ALPHA 0.1f

// ---------------- lin0: h0 = relu(x @ W0 + b0) ----------------
__global__ __launch_bounds__(256) void lin0_k(const float* __restrict__ x, const float* __restrict__ W0,
                                              const float* __restrict__ b0, float* __restrict__ h0) {
    int t = blockIdx.x * 256 + threadIdx.x;
    if (t >= N_NODES * HID) return;
    int node = t / HID, f = t % HID;
    float v = b0[f]
            + x[node * 3 + 0] * W0[0 * HID + f]
            + x[node * 3 + 1] * W0[1 * HID + f]
            + x[node * 3 + 2] * W0[2 * HID + f];
    h0[t] = v > 0.f ? v : 0.f;
}

// ---------------- CSR build ----------------
__global__ __launch_bounds__(256) void count_k(const int* __restrict__ dst, int* __restrict__ deg) {
    int e = blockIdx.x * 256 + threadIdx.x;
    if (e < N_EDGES) atomicAdd(&deg[dst[e]], 1);
}

// block scans 2048 elements (256 thr x 8)
__global__ __launch_bounds__(256) void scan1_k(const int* __restrict__ deg, int* __restrict__ rowptr,
                                               int* __restrict__ partial) {
    __shared__ int sums[256];
    int tid = threadIdx.x;
    int base = blockIdx.x * 2048 + tid * 8;
    int v[8]; int s = 0;
#pragma unroll
    for (int j = 0; j < 8; j++) { int idx = base + j; v[j] = (idx < N_NODES) ? deg[idx] : 0; s += v[j]; }
    sums[tid] = s; __syncthreads();
    for (int off = 1; off < 256; off <<= 1) {
        int t = (tid >= off) ? sums[tid - off] : 0;
        __syncthreads();
        sums[tid] += t;
        __syncthreads();
    }
    if (tid == 255) partial[blockIdx.x] = sums[255];
    int run = (tid > 0) ? sums[tid - 1] : 0;
#pragma unroll
    for (int j = 0; j < 8; j++) { int idx = base + j; if (idx < N_NODES) rowptr[idx] = run; run += v[j]; }
}

__global__ void scan2_k(int* __restrict__ partial, int* __restrict__ rowptr, int nblk) {
    if (threadIdx.x == 0 && blockIdx.x == 0) {
        int acc = 0;
        for (int i = 0; i < nblk; i++) { int t = partial[i]; partial[i] = acc; acc += t; }
        rowptr[N_NODES] = acc;
    }
}

__global__ __launch_bounds__(256) void scan3_k(int* __restrict__ rowptr, int* __restrict__ cursor,
                                               const int* __restrict__ partial) {
    int tid = threadIdx.x;
    int base = blockIdx.x * 2048 + tid * 8;
    int add = partial[blockIdx.x];
#pragma unroll
    for (int j = 0; j < 8; j++) {
        int idx = base + j;
        if (idx < N_NODES) { int v = rowptr[idx] + add; rowptr[idx] = v; cursor[idx] = v; }
    }
}

__global__ __launch_bounds__(256) void bucket_k(const int* __restrict__ src, const int* __restrict__ dst,
                                                int* __restrict__ cursor, int* __restrict__ ssrc) {
    int e = blockIdx.x * 256 + threadIdx.x;
    if (e < N_EDGES) {
        int s = src[e], d = dst[e];
        int p = atomicAdd(&cursor[d], 1);
        ssrc[p] = s;
    }
}

// ---------------- fused layer: agg(CSR gather) + GCNII combine + 48x48 matmul + relu ----------------
// one wave per node; lanes 0..47 = features
__global__ __launch_bounds__(256) void layer_k(const float* __restrict__ h_in, const float* __restrict__ x0,
                                               const int* __restrict__ rowptr, const int* __restrict__ ssrc,
                                               const float* __restrict__ W, float beta,
                                               float* __restrict__ h_out) {
    __shared__ float tbuf[4][48];
    int tid = threadIdx.x, wave = tid >> 6, lane = tid & 63;
    int node = blockIdx.x * 4 + wave;
    int f = lane < 48 ? lane : 0;
    float Wc[48];
#pragma unroll
    for (int k = 0; k < 48; k++) Wc[k] = W[k * 48 + f];
    if (node < N_NODES) {
        float acc = 0.f;
        int e0 = rowptr[node], e1 = rowptr[node + 1];
        for (int e = e0; e < e1; e++) {
            int s = ssrc[e];
            acc += h_in[s * 48 + f];
        }
        float t = (1.f - ALPHA) * acc + ALPHA * x0[node * 48 + f];
        if (lane < 48) tbuf[wave][lane] = t;
    }
    __syncthreads();
    if (node < N_NODES && lane < 48) {
        const float4* t4 = (const float4*)tbuf[wave];
        float s = 0.f;
#pragma unroll
        for (int k4 = 0; k4 < 12; k4++) {
            float4 tv = t4[k4];
            s += tv.x * Wc[4 * k4 + 0] + tv.y * Wc[4 * k4 + 1] + tv.z * Wc[4 * k4 + 2] + tv.w * Wc[4 * k4 + 3];
        }
        float t = tbuf[wave][lane];
        float o = (1.f - beta) * t + beta * s;
        h_out[node * 48 + lane] = o > 0.f ? o : 0.f;
    }
}

// ---------------- final: out = log_softmax(h @ W1 + b1) ----------------
__global__ __launch_bounds__(256) void final_k(const float* __restrict__ h, const float* __restrict__ W1,
                                               const float* __restrict__ b1, float* __restrict__ out) {
    __shared__ float tbuf[4][48];
    int tid = threadIdx.x, wave = tid >> 6, lane = tid & 63;
    int node = blockIdx.x * 4 + wave;
    int f = lane < 48 ? lane : 0;
    float Wc[48];
#pragma unroll
    for (int k = 0; k < 48; k++) Wc[k] = W1[k * 48 + f];
    if (node < N_NODES && lane < 48) tbuf[wave][lane] = h[node * 48 + lane];
    __syncthreads();
    float v = -INFINITY;
    if (node < N_NODES) {
        const float4* t4 = (const float4*)tbuf[wave];
        float s = b1[f];
#pragma unroll
        for (int k4 = 0; k4 < 12; k4++) {
            float4 tv = t4[k4];
            s += tv.x * Wc[4 * k4 + 0] + tv.y * Wc[4 * k4 + 1] + tv.z * Wc[4 * k4 + 2] + tv.w * Wc[4 * k4 + 3];
        }
        if (lane < 48) v = s;
    }
    // wave-wide (64-lane) reductions; lanes 48..63 hold identities
    float m = v;
    for (int off = 32; off >= 1; off >>= 1) m = fmaxf(m, __shfl_xor(m, off));
    float ex = (node < N_NODES && lane < 48) ? expf(v - m) : 0.f;
    float sum = ex;
    for (int off = 32; off >= 1; off >>= 1) sum += __shfl_xor(sum, off);
    if (node < N_NODES && lane < 48) {
        out[node * 48 + lane] = v - m - logf(sum);
    }
}

extern "C" void kernel_launch(void* const* d_in, const int* in_sizes, int n_in,
                              void* d_out, int out_size, void* d_ws, size_t ws_size,
                              hipStream_t stream) {
    const float* x     = (const float*)d_in[0];
    const int*   ei    = (const int*)d_in[1];
    const float* W0    = (const float*)d_in[2];
    const float* b0    = (const float*)d_in[3];
    const float* convW = (const float*)d_in[4];
    const float* W1    = (const float*)d_in[5];
    const float* b1    = (const float*)d_in[6];
    float* out = (float*)d_out;
    const int* src = ei;            // edge_index[0]
    const int* dst = ei + N_EDGES;  // edge_index[1]

    char* ws = (char*)d_ws;
    size_t off = 0;
    float* x0 = (float*)(ws + off); off += (size_t)N_NODES * 48 * 4;   // 19.2 MB
    float* hA = (float*)(ws + off); off += (size_t)N_NODES * 48 * 4;   // 19.2 MB
    int* ssrc = (int*)(ws + off);   off += (size_t)N_EDGES * 4;        // 6.4 MB
    int* rowptr = (int*)(ws + off); off += (size_t)(N_NODES + 1) * 4;
    off = (off + 255) & ~(size_t)255;
    int* cursor = (int*)(ws + off); off += (size_t)N_NODES * 4;
    off = (off + 255) & ~(size_t)255;
    int* deg = (int*)(ws + off);    off += (size_t)N_NODES * 4;
    off = (off + 255) & ~(size_t)255;
    int* partial = (int*)(ws + off); off += 64 * 4;

    hipMemsetAsync(deg, 0, (size_t)N_NODES * 4, stream);

    lin0_k<<<18750, 256, 0, stream>>>(x, W0, b0, x0);
    count_k<<<6250, 256, 0, stream>>>(dst, deg);
    scan1_k<<<49, 256, 0, stream>>>(deg, rowptr, partial);
    scan2_k<<<1, 64, 0, stream>>>(partial, rowptr, 49);
    scan3_k<<<49, 256, 0, stream>>>(rowptr, cursor, partial);
    bucket_k<<<6250, 256, 0, stream>>>(src, dst, cursor, ssrc);

    const float betas[4] = { logf(1.5f), logf(1.25f), logf(7.f / 6.f), logf(1.125f) };

    // ping-pong: x0 -> hA -> out -> hA -> out; final in-place on out
    layer_k<<<25000, 256, 0, stream>>>(x0,  x0, rowptr, ssrc, convW + 0 * 2304, betas[0], hA);
    layer_k<<<25000, 256, 0, stream>>>(hA,  x0, rowptr, ssrc, convW + 1 * 2304, betas[1], out);
    layer_k<<<25000, 256, 0, stream>>>(out, x0, rowptr, ssrc, convW + 2 * 2304, betas[2], hA);
    layer_k<<<25000, 256, 0, stream>>>(hA,  x0, rowptr, ssrc, convW + 3 * 2304, betas[3], out);
    final_k<<<25000, 256, 0, stream>>>(out, W1, b1, out);
}

// Round 2
// 691.979 us; speedup vs baseline: 1.4649x; 1.4649x over previous
//
#include <hip/hip_runtime.h>
#include <math.h>

#define N_NODES 100000
#define N_EDGES 1600000
#define HID 48
#define ALPHA 0.1f

typedef unsigned short u16;

__device__ __forceinline__ float bf2f(u16 u) {
    return __uint_as_float(((unsigned int)u) << 16);
}
__device__ __forceinline__ u16 f2bf(float f) {
    unsigned int b = __float_as_uint(f);
    b += 0x7fff + ((b >> 16) & 1);   // round-to-nearest-even
    return (u16)(b >> 16);
}

// ---------------- lin0: h0 = relu(x @ W0 + b0); writes f32 x0 AND bf16 h0 ----------------
__global__ __launch_bounds__(256) void lin0_k(const float* __restrict__ x, const float* __restrict__ W0,
                                              const float* __restrict__ b0, float* __restrict__ x0f,
                                              u16* __restrict__ h0) {
    int t = blockIdx.x * 256 + threadIdx.x;
    if (t >= N_NODES * HID) return;
    int node = t / HID, f = t % HID;
    float v = b0[f]
            + x[node * 3 + 0] * W0[0 * HID + f]
            + x[node * 3 + 1] * W0[1 * HID + f]
            + x[node * 3 + 2] * W0[2 * HID + f];
    v = v > 0.f ? v : 0.f;
    x0f[t] = v;
    h0[t] = f2bf(v);
}

// ---------------- CSR build ----------------
__global__ __launch_bounds__(256) void count_k(const int* __restrict__ dst, int* __restrict__ deg) {
    int e = blockIdx.x * 256 + threadIdx.x;
    if (e < N_EDGES) atomicAdd(&deg[dst[e]], 1);
}

__global__ __launch_bounds__(256) void scan1_k(const int* __restrict__ deg, int* __restrict__ rowptr,
                                               int* __restrict__ partial) {
    __shared__ int sums[256];
    int tid = threadIdx.x;
    int base = blockIdx.x * 2048 + tid * 8;
    int v[8]; int s = 0;
#pragma unroll
    for (int j = 0; j < 8; j++) { int idx = base + j; v[j] = (idx < N_NODES) ? deg[idx] : 0; s += v[j]; }
    sums[tid] = s; __syncthreads();
    for (int off = 1; off < 256; off <<= 1) {
        int t = (tid >= off) ? sums[tid - off] : 0;
        __syncthreads();
        sums[tid] += t;
        __syncthreads();
    }
    if (tid == 255) partial[blockIdx.x] = sums[255];
    int run = (tid > 0) ? sums[tid - 1] : 0;
#pragma unroll
    for (int j = 0; j < 8; j++) { int idx = base + j; if (idx < N_NODES) rowptr[idx] = run; run += v[j]; }
}

__global__ void scan2_k(int* __restrict__ partial, int* __restrict__ rowptr, int nblk) {
    if (threadIdx.x == 0 && blockIdx.x == 0) {
        int acc = 0;
        for (int i = 0; i < nblk; i++) { int t = partial[i]; partial[i] = acc; acc += t; }
        rowptr[N_NODES] = acc;
    }
}

__global__ __launch_bounds__(256) void scan3_k(int* __restrict__ rowptr, int* __restrict__ cursor,
                                               const int* __restrict__ partial) {
    int tid = threadIdx.x;
    int base = blockIdx.x * 2048 + tid * 8;
    int add = partial[blockIdx.x];
#pragma unroll
    for (int j = 0; j < 8; j++) {
        int idx = base + j;
        if (idx < N_NODES) { int v = rowptr[idx] + add; rowptr[idx] = v; cursor[idx] = v; }
    }
}

__global__ __launch_bounds__(256) void bucket_k(const int* __restrict__ src, const int* __restrict__ dst,
                                                int* __restrict__ cursor, int* __restrict__ ssrc) {
    int e = blockIdx.x * 256 + threadIdx.x;
    if (e < N_EDGES) {
        int s = src[e], d = dst[e];
        int p = atomicAdd(&cursor[d], 1);
        ssrc[p] = s;
    }
}

// ---------------- fused layer: CSR gather (bf16, 8x unrolled) + GCNII combine + 48x48 matmul + relu ----
// one wave per node; lanes 0..47 = features
__global__ __launch_bounds__(256) void layer_k(const u16* __restrict__ h_in, const float* __restrict__ x0,
                                               const int* __restrict__ rowptr, const int* __restrict__ ssrc,
                                               const float* __restrict__ W, float beta,
                                               u16* __restrict__ h_out) {
    __shared__ float tbuf[4][48];
    int tid = threadIdx.x, wave = tid >> 6, lane = tid & 63;
    int node = blockIdx.x * 4 + wave;
    int f = lane < 48 ? lane : 0;
    if (node < N_NODES) {
        int e0 = rowptr[node], e1 = rowptr[node + 1];
        float xv = x0[node * 48 + f];
        float acc = 0.f;
        int e = e0;
        // 8-wide unroll: 8 independent gathers in flight per wave
        for (; e + 8 <= e1; e += 8) {
            int s0 = ssrc[e + 0], s1 = ssrc[e + 1], s2 = ssrc[e + 2], s3 = ssrc[e + 3];
            int s4 = ssrc[e + 4], s5 = ssrc[e + 5], s6 = ssrc[e + 6], s7 = ssrc[e + 7];
            float a0 = bf2f(h_in[s0 * 48 + f]);
            float a1 = bf2f(h_in[s1 * 48 + f]);
            float a2 = bf2f(h_in[s2 * 48 + f]);
            float a3 = bf2f(h_in[s3 * 48 + f]);
            float a4 = bf2f(h_in[s4 * 48 + f]);
            float a5 = bf2f(h_in[s5 * 48 + f]);
            float a6 = bf2f(h_in[s6 * 48 + f]);
            float a7 = bf2f(h_in[s7 * 48 + f]);
            acc += ((a0 + a1) + (a2 + a3)) + ((a4 + a5) + (a6 + a7));
        }
        for (; e < e1; e++) {
            acc += bf2f(h_in[ssrc[e] * 48 + f]);
        }
        float t = (1.f - ALPHA) * acc + ALPHA * xv;
        if (lane < 48) tbuf[wave][lane] = t;
    }
    __syncthreads();
    if (node < N_NODES && lane < 48) {
        const float4* t4 = (const float4*)tbuf[wave];
        float s = 0.f;
#pragma unroll
        for (int k4 = 0; k4 < 12; k4++) {
            float4 tv = t4[k4];
            s += tv.x * W[(4 * k4 + 0) * 48 + lane] + tv.y * W[(4 * k4 + 1) * 48 + lane]
               + tv.z * W[(4 * k4 + 2) * 48 + lane] + tv.w * W[(4 * k4 + 3) * 48 + lane];
        }
        float t = tbuf[wave][lane];
        float o = (1.f - beta) * t + beta * s;
        h_out[node * 48 + lane] = f2bf(o > 0.f ? o : 0.f);
    }
}

// ---------------- final: out = log_softmax(h @ W1 + b1) ----------------
__global__ __launch_bounds__(256) void final_k(const u16* __restrict__ h, const float* __restrict__ W1,
                                               const float* __restrict__ b1, float* __restrict__ out) {
    __shared__ float tbuf[4][48];
    int tid = threadIdx.x, wave = tid >> 6, lane = tid & 63;
    int node = blockIdx.x * 4 + wave;
    int f = lane < 48 ? lane : 0;
    if (node < N_NODES && lane < 48) tbuf[wave][lane] = bf2f(h[node * 48 + lane]);
    __syncthreads();
    float v = -INFINITY;
    if (node < N_NODES) {
        const float4* t4 = (const float4*)tbuf[wave];
        float s = b1[f];
#pragma unroll
        for (int k4 = 0; k4 < 12; k4++) {
            float4 tv = t4[k4];
            s += tv.x * W1[(4 * k4 + 0) * 48 + f] + tv.y * W1[(4 * k4 + 1) * 48 + f]
               + tv.z * W1[(4 * k4 + 2) * 48 + f] + tv.w * W1[(4 * k4 + 3) * 48 + f];
        }
        if (lane < 48) v = s;
    }
    float m = v;
    for (int off = 32; off >= 1; off >>= 1) m = fmaxf(m, __shfl_xor(m, off));
    float ex = (node < N_NODES && lane < 48) ? expf(v - m) : 0.f;
    float sum = ex;
    for (int off = 32; off >= 1; off >>= 1) sum += __shfl_xor(sum, off);
    if (node < N_NODES && lane < 48) {
        out[node * 48 + lane] = v - m - logf(sum);
    }
}

extern "C" void kernel_launch(void* const* d_in, const int* in_sizes, int n_in,
                              void* d_out, int out_size, void* d_ws, size_t ws_size,
                              hipStream_t stream) {
    const float* x     = (const float*)d_in[0];
    const int*   ei    = (const int*)d_in[1];
    const float* W0    = (const float*)d_in[2];
    const float* b0    = (const float*)d_in[3];
    const float* convW = (const float*)d_in[4];
    const float* W1    = (const float*)d_in[5];
    const float* b1    = (const float*)d_in[6];
    float* out = (float*)d_out;
    const int* src = ei;            // edge_index[0]
    const int* dst = ei + N_EDGES;  // edge_index[1]

    char* ws = (char*)d_ws;
    size_t off = 0;
    float* x0 = (float*)(ws + off); off += (size_t)N_NODES * 48 * 4;   // 19.2 MB f32 residual
    u16* hA   = (u16*)(ws + off);   off += (size_t)N_NODES * 48 * 2;   // 9.6 MB bf16
    u16* hB   = (u16*)(ws + off);   off += (size_t)N_NODES * 48 * 2;   // 9.6 MB bf16
    int* ssrc = (int*)(ws + off);   off += (size_t)N_EDGES * 4;        // 6.4 MB
    int* rowptr = (int*)(ws + off); off += (size_t)(N_NODES + 1) * 4;
    off = (off + 255) & ~(size_t)255;
    int* cursor = (int*)(ws + off); off += (size_t)N_NODES * 4;
    off = (off + 255) & ~(size_t)255;
    int* deg = (int*)(ws + off);    off += (size_t)N_NODES * 4;
    off = (off + 255) & ~(size_t)255;
    int* partial = (int*)(ws + off); off += 64 * 4;

    hipMemsetAsync(deg, 0, (size_t)N_NODES * 4, stream);

    lin0_k<<<18750, 256, 0, stream>>>(x, W0, b0, x0, hA);
    count_k<<<6250, 256, 0, stream>>>(dst, deg);
    scan1_k<<<49, 256, 0, stream>>>(deg, rowptr, partial);
    scan2_k<<<1, 64, 0, stream>>>(partial, rowptr, 49);
    scan3_k<<<49, 256, 0, stream>>>(rowptr, cursor, partial);
    bucket_k<<<6250, 256, 0, stream>>>(src, dst, cursor, ssrc);

    const float betas[4] = { logf(1.5f), logf(1.25f), logf(7.f / 6.f), logf(1.125f) };

    layer_k<<<25000, 256, 0, stream>>>(hA, x0, rowptr, ssrc, convW + 0 * 2304, betas[0], hB);
    layer_k<<<25000, 256, 0, stream>>>(hB, x0, rowptr, ssrc, convW + 1 * 2304, betas[1], hA);
    layer_k<<<25000, 256, 0, stream>>>(hA, x0, rowptr, ssrc, convW + 2 * 2304, betas[2], hB);
    layer_k<<<25000, 256, 0, stream>>>(hB, x0, rowptr, ssrc, convW + 3 * 2304, betas[3], hA);
    final_k<<<25000, 256, 0, stream>>>(hA, W1, b1, out);
}